// Round 8
// baseline (756.126 us; speedup 1.0000x reference)
//
#include <hip/hip_runtime.h>

// Problem constants
#define BB   512
#define CC   22
#define TT   1000
#define HH   64
#define NCLS 4
#define FCW  (TT * HH)       // 64000: W_fc row length
#define TB   100             // t-tile per xproj block (10 tiles)

typedef _Float16 f16;
typedef __attribute__((ext_vector_type(2))) _Float16 h2;

__device__ __forceinline__ float sigm(float x) {
    float e = __expf(-x);
    return __builtin_amdgcn_rcpf(1.0f + e);
}
__device__ __forceinline__ float tanh_(float x) {
    float e = __expf(-2.0f * fabsf(x));   // (0,1], no overflow
    float r = (1.0f - e) * __builtin_amdgcn_rcpf(1.0f + e);
    return copysignf(r, x);
}
__device__ __forceinline__ h2 u2h(unsigned u) {
    union { unsigned u; h2 h; } c; c.u = u; return c.h;
}
__device__ __forceinline__ unsigned h2u(h2 h) {
    union { unsigned u; h2 h; } c; c.h = h; return c.u;
}
__device__ __forceinline__ unsigned pack2(float a, float b) {
    union { unsigned u; h2 h; } c;
    c.h = h2{(f16)a, (f16)b};
    return c.u;
}

// ---------------------------------------------------------------------------
// R12 kernel 1: x-projection precompute (rewritten from R11's 190us version).
// Thread <-> (t-half, hid, gate-PAIR): each thread computes gates {2gp, 2gp+1}
// for its hid over half the t-tile, storing ONE coalesced 4B uint per t
// (R11 stored 4 scattered 2B f16 -> 4x the store instrs and 2x the per-thread
// dot work per output byte). t-halves interleave in 4-step groups so the
// xt float4 reads stay 16B-aligned.
// Output layout matches lstm_rec's unpack: uint at slot hid*2+gp of (b,t),
// gp=0 -> pack2(i,f), gp=1 -> pack2(g,o).
// ---------------------------------------------------------------------------
__global__ __launch_bounds__(256) void xproj(
    const float* __restrict__ x,     // [B, C, T]
    const float* __restrict__ W_ih,  // [4H, C]
    const float* __restrict__ b_ih,  // [4H]
    const float* __restrict__ b_hh,  // [4H]
    unsigned* __restrict__ xp)       // [B, T, 128] uints
{
    __shared__ __align__(16) float xt[CC][TB];   // 8.8 KB

    const int tid = threadIdx.x;
    const int t0  = blockIdx.x * TB;
    const int b   = blockIdx.y;
    const int th  = tid >> 7;        // t-half (interleaved by 4)
    const int p   = tid & 127;
    const int hid = p >> 1;
    const int gp  = p & 1;
    const int ra  = (2 * gp) * HH + hid;       // gate 2gp
    const int rb  = (2 * gp + 1) * HH + hid;   // gate 2gp+1

    // stage x[b][:, t0..t0+TB) -- coalesced along t
    for (int s = tid; s < CC * TB; s += 256) {
        const int c = s / TB, t = s - c * TB;
        xt[c][t] = x[((size_t)b * CC + c) * TT + t0 + t];
    }
    // this thread's two W_ih rows + folded biases (one-time scalar loads)
    float wa[CC], wb[CC];
    #pragma unroll
    for (int c = 0; c < CC; ++c) {
        wa[c] = W_ih[ra * CC + c];
        wb[c] = W_ih[rb * CC + c];
    }
    const float ba = b_ih[ra] + b_hh[ra];
    const float bb = b_ih[rb] + b_hh[rb];
    __syncthreads();

    unsigned* op = xp + ((size_t)b * TT + t0) * 128 + p;
    for (int tb = th * 4; tb < TB; tb += 8) {
        float a0 = ba, a1 = ba, a2 = ba, a3 = ba;
        float c0 = bb, c1 = bb, c2 = bb, c3 = bb;
        #pragma unroll
        for (int c = 0; c < CC; ++c) {
            const float4 xv = *(const float4*)&xt[c][tb];   // broadcast b128
            a0 += wa[c] * xv.x; a1 += wa[c] * xv.y;
            a2 += wa[c] * xv.z; a3 += wa[c] * xv.w;
            c0 += wb[c] * xv.x; c1 += wb[c] * xv.y;
            c2 += wb[c] * xv.z; c3 += wb[c] * xv.w;
        }
        op[(size_t)(tb + 0) * 128] = pack2(a0, c0);
        op[(size_t)(tb + 1) * 128] = pack2(a1, c1);
        op[(size_t)(tb + 2) * 128] = pack2(a2, c2);
        op[(size_t)(tb + 3) * 128] = pack2(a3, c3);
    }
}

// ---------------------------------------------------------------------------
// R12 kernel 2: single-wave recurrence, software-pipelined.
// R11 counters: 1285 cyc/step = ~790 issue (VALUBusy 30.7% at 2-wave/CU
// coverage) + ~495 exposed stall. FETCH=132MB proves the xp stream misses to
// L3/HBM -> the per-step xp load (~600-900 cyc) has only the ~256-cyc fdot
// chain to hide under. Fix: unroll t by 2, prefetch xp and W_fc TWO steps
// ahead into named rotated registers (slack ~= one body ~1600 cyc > latency).
// Gate accumulators now INIT from the (long-arrived) xp value instead of a
// late add: saves 4 v_add/step and removes the end-of-chain dependency.
// ---------------------------------------------------------------------------
__global__ __attribute__((amdgpu_waves_per_eu(1, 1)))
__launch_bounds__(64) void lstm_rec(
    const uint2* __restrict__ xp,    // [B, T, H] as uint2 (4 f16 gates)
    const float* __restrict__ W_hh,  // [4H, H]
    const float* __restrict__ W_fc,  // [NCLS, T*H]
    const float* __restrict__ b_fc,  // [NCLS]
    float* __restrict__ out)         // [B, NCLS]
{
    __shared__ __align__(16) f16 hbuf[HH];   // 128 B: h broadcast

    const int lane = threadIdx.x;    // hidden unit
    const int r    = blockIdx.x;     // batch row

    // per-lane recurrent weights (128 VGPR), pinned resident
    unsigned whh[4][32];
    #pragma unroll
    for (int g = 0; g < 4; ++g) {
        const float* wr = W_hh + (g * HH + lane) * HH;
        #pragma unroll
        for (int k = 0; k < 32; ++k)
            whh[g][k] = h2u(h2{(f16)wr[2 * k], (f16)wr[2 * k + 1]});
    }
    #pragma unroll
    for (int g = 0; g < 4; ++g)
        #pragma unroll
        for (int k = 0; k < 32; ++k) asm volatile("" : "+v"(whh[g][k]));

    hbuf[lane] = (f16)0.0f;          // own-wave in-order DS; no barrier
    float c = 0.0f;
    float fc0 = 0.f, fc1 = 0.f, fc2 = 0.f, fc3 = 0.f;
    const uint2* px = xp + (size_t)r * TT * HH + lane;
    const float* pf0 = W_fc + 0 * FCW + lane;
    const float* pf1 = W_fc + 1 * FCW + lane;
    const float* pf2 = W_fc + 2 * FCW + lane;
    const float* pf3 = W_fc + 3 * FCW + lane;

    // pipeline prologue: steps 0 and 1 pre-loaded
    uint2 xvA = px[0];
    uint2 xvB = px[HH];
    float wA0 = pf0[0],  wA1 = pf1[0],  wA2 = pf2[0],  wA3 = pf3[0];
    float wB0 = pf0[HH], wB1 = pf1[HH], wB2 = pf2[HH], wB3 = pf3[HH];

    for (int t = 0; t < TT; t += 2) {
        // ---- prefetch steps t+2, t+3 (clamped; issued ~1 body ahead) ----
        const size_t o2 = (size_t)((t + 2 < TT) ? t + 2 : TT - 1) * HH;
        const size_t o3 = (size_t)((t + 3 < TT) ? t + 3 : TT - 1) * HH;
        const uint2 xv2 = px[o2];
        const uint2 xv3 = px[o3];
        const float w20 = pf0[o2], w21 = pf1[o2], w22 = pf2[o2], w23 = pf3[o2];
        const float w30 = pf0[o3], w31 = pf1[o3], w32 = pf2[o3], w33 = pf3[o3];

        // ================= step t =================
        {
            union { uint4 q[8]; h2 h[32]; } H;
            const uint4* hr = (const uint4*)hbuf;
            #pragma unroll
            for (int i = 0; i < 8; ++i) H.q[i] = hr[i];

            const h2 pif = u2h(xvA.x), pgo = u2h(xvA.y);
            float a0 = (float)pif[0], a1 = (float)pif[1];
            float a2 = (float)pgo[0], a3 = (float)pgo[1];
            #pragma unroll
            for (int k = 0; k < 32; ++k) {
                a0 = __builtin_amdgcn_fdot2(H.h[k], u2h(whh[0][k]), a0, false);
                a1 = __builtin_amdgcn_fdot2(H.h[k], u2h(whh[1][k]), a1, false);
                a2 = __builtin_amdgcn_fdot2(H.h[k], u2h(whh[2][k]), a2, false);
                a3 = __builtin_amdgcn_fdot2(H.h[k], u2h(whh[3][k]), a3, false);
            }
            const float iv = sigm(a0), fv = sigm(a1);
            const float gv = tanh_(a2), ov = sigm(a3);
            c = fv * c + iv * gv;
            const float h = ov * tanh_(c);
            fc0 += h * wA0; fc1 += h * wA1; fc2 += h * wA2; fc3 += h * wA3;
            hbuf[lane] = (f16)h;
        }
        // ================= step t+1 =================
        {
            union { uint4 q[8]; h2 h[32]; } H;
            const uint4* hr = (const uint4*)hbuf;
            #pragma unroll
            for (int i = 0; i < 8; ++i) H.q[i] = hr[i];

            const h2 pif = u2h(xvB.x), pgo = u2h(xvB.y);
            float a0 = (float)pif[0], a1 = (float)pif[1];
            float a2 = (float)pgo[0], a3 = (float)pgo[1];
            #pragma unroll
            for (int k = 0; k < 32; ++k) {
                a0 = __builtin_amdgcn_fdot2(H.h[k], u2h(whh[0][k]), a0, false);
                a1 = __builtin_amdgcn_fdot2(H.h[k], u2h(whh[1][k]), a1, false);
                a2 = __builtin_amdgcn_fdot2(H.h[k], u2h(whh[2][k]), a2, false);
                a3 = __builtin_amdgcn_fdot2(H.h[k], u2h(whh[3][k]), a3, false);
            }
            const float iv = sigm(a0), fv = sigm(a1);
            const float gv = tanh_(a2), ov = sigm(a3);
            c = fv * c + iv * gv;
            const float h = ov * tanh_(c);
            fc0 += h * wB0; fc1 += h * wB1; fc2 += h * wB2; fc3 += h * wB3;
            hbuf[lane] = (f16)h;
        }

        // rotate pipeline registers (all static names)
        xvA = xv2; xvB = xv3;
        wA0 = w20; wA1 = w21; wA2 = w22; wA3 = w23;
        wB0 = w30; wB1 = w31; wB2 = w32; wB3 = w33;
    }

    // FC reduce over hid (wave shuffle) + softmax
    #pragma unroll
    for (int off = 32; off; off >>= 1) {
        fc0 += __shfl_down(fc0, off);
        fc1 += __shfl_down(fc1, off);
        fc2 += __shfl_down(fc2, off);
        fc3 += __shfl_down(fc3, off);
    }
    if (lane == 0) {
        const float l0 = fc0 + b_fc[0], l1 = fc1 + b_fc[1];
        const float l2 = fc2 + b_fc[2], l3 = fc3 + b_fc[3];
        const float m  = fmaxf(fmaxf(l0, l1), fmaxf(l2, l3));
        const float e0 = __expf(l0 - m), e1 = __expf(l1 - m);
        const float e2 = __expf(l2 - m), e3 = __expf(l3 - m);
        const float is = __builtin_amdgcn_rcpf(e0 + e1 + e2 + e3);
        float4 o; o.x = e0 * is; o.y = e1 * is; o.z = e2 * is; o.w = e3 * is;
        *(float4*)(out + r * NCLS) = o;
    }
}

// ---------------------------------------------------------------------------
// Fallback: self-contained single kernel (R4 structure), used only if the
// workspace can't hold xp (262 MB).
// ---------------------------------------------------------------------------
#define TC   250
#define NCHUNK (TT / TC)
#define XROW 12

__global__ __attribute__((amdgpu_waves_per_eu(1, 1)))
__launch_bounds__(64) void lstm_fb(
    const float* __restrict__ x, const float* __restrict__ W_ih,
    const float* __restrict__ W_hh, const float* __restrict__ b_ih,
    const float* __restrict__ b_hh, const float* __restrict__ W_fc,
    const float* __restrict__ b_fc, float* __restrict__ out)
{
    __shared__ __align__(16) h2  xs[TC][XROW];
    __shared__ __align__(16) f16 hbuf[HH];

    const int lane = threadIdx.x;
    const int r    = blockIdx.x;

    unsigned whh[4][32];
    unsigned wih[4][11];
    float bias[4];
    #pragma unroll
    for (int g = 0; g < 4; ++g) {
        const int row = g * HH + lane;
        const float* wr = W_hh + row * HH;
        #pragma unroll
        for (int k = 0; k < 32; ++k)
            whh[g][k] = h2u(h2{(f16)wr[2 * k], (f16)wr[2 * k + 1]});
        const float* wi = W_ih + row * CC;
        #pragma unroll
        for (int k = 0; k < 11; ++k)
            wih[g][k] = h2u(h2{(f16)wi[2 * k], (f16)wi[2 * k + 1]});
        bias[g] = b_ih[row] + b_hh[row];
    }
    #pragma unroll
    for (int g = 0; g < 4; ++g) {
        #pragma unroll
        for (int k = 0; k < 32; ++k) asm volatile("" : "+v"(whh[g][k]));
        #pragma unroll
        for (int k = 0; k < 11; ++k) asm volatile("" : "+v"(wih[g][k]));
        asm volatile("" : "+v"(bias[g]));
    }

    hbuf[lane] = (f16)0.0f;
    float c = 0.0f;
    float fc0 = 0.f, fc1 = 0.f, fc2 = 0.f, fc3 = 0.f;
    const float* p0 = W_fc + 0 * FCW + lane;
    const float* p1 = W_fc + 1 * FCW + lane;
    const float* p2 = W_fc + 2 * FCW + lane;
    const float* p3 = W_fc + 3 * FCW + lane;
    const float* xrow = x + (size_t)r * (CC * TT);

    for (int chunk = 0; chunk < NCHUNK; ++chunk) {
        for (int tb = 0; tb < TC; tb += 64) {
            const int t = tb + lane;
            if (t < TC) {
                const float* gx = xrow + chunk * TC + t;
                union { h2 h[XROW]; uint4 q[3]; } U;
                #pragma unroll
                for (int k = 0; k < 11; ++k)
                    U.h[k] = h2{(f16)gx[(2 * k) * TT], (f16)gx[(2 * k + 1) * TT]};
                U.h[11] = h2{(f16)0.0f, (f16)0.0f};
                uint4* dst = (uint4*)&xs[t][0];
                dst[0] = U.q[0]; dst[1] = U.q[1]; dst[2] = U.q[2];
            }
        }
        for (int tt = 0; tt < TC; ++tt) {
            union { uint4 q[8]; h2 h[32]; } H;
            const uint4* hr = (const uint4*)hbuf;
            #pragma unroll
            for (int i = 0; i < 8; ++i) H.q[i] = hr[i];
            union { uint4 q[3]; h2 h[XROW]; } X;
            const uint4* xr = (const uint4*)&xs[tt][0];
            X.q[0] = xr[0]; X.q[1] = xr[1]; X.q[2] = xr[2];
            float w0 = *p0, w1 = *p1, w2 = *p2, w3 = *p3;
            p0 += HH; p1 += HH; p2 += HH; p3 += HH;
            float a0 = bias[0], a1 = bias[1], a2 = bias[2], a3 = bias[3];
            #pragma unroll
            for (int k = 0; k < 11; ++k) {
                a0 = __builtin_amdgcn_fdot2(X.h[k], u2h(wih[0][k]), a0, false);
                a1 = __builtin_amdgcn_fdot2(X.h[k], u2h(wih[1][k]), a1, false);
                a2 = __builtin_amdgcn_fdot2(X.h[k], u2h(wih[2][k]), a2, false);
                a3 = __builtin_amdgcn_fdot2(X.h[k], u2h(wih[3][k]), a3, false);
            }
            #pragma unroll
            for (int k = 0; k < 32; ++k) {
                a0 = __builtin_amdgcn_fdot2(H.h[k], u2h(whh[0][k]), a0, false);
                a1 = __builtin_amdgcn_fdot2(H.h[k], u2h(whh[1][k]), a1, false);
                a2 = __builtin_amdgcn_fdot2(H.h[k], u2h(whh[2][k]), a2, false);
                a3 = __builtin_amdgcn_fdot2(H.h[k], u2h(whh[3][k]), a3, false);
            }
            const float iv = sigm(a0), fv = sigm(a1);
            const float gv = tanh_(a2), ov = sigm(a3);
            c = fv * c + iv * gv;
            const float h = ov * tanh_(c);
            fc0 += h * w0; fc1 += h * w1; fc2 += h * w2; fc3 += h * w3;
            hbuf[lane] = (f16)h;
        }
    }
    #pragma unroll
    for (int off = 32; off; off >>= 1) {
        fc0 += __shfl_down(fc0, off);
        fc1 += __shfl_down(fc1, off);
        fc2 += __shfl_down(fc2, off);
        fc3 += __shfl_down(fc3, off);
    }
    if (lane == 0) {
        const float l0 = fc0 + b_fc[0], l1 = fc1 + b_fc[1];
        const float l2 = fc2 + b_fc[2], l3 = fc3 + b_fc[3];
        const float m  = fmaxf(fmaxf(l0, l1), fmaxf(l2, l3));
        const float e0 = __expf(l0 - m), e1 = __expf(l1 - m);
        const float e2 = __expf(l2 - m), e3 = __expf(l3 - m);
        const float is = __builtin_amdgcn_rcpf(e0 + e1 + e2 + e3);
        float4 o; o.x = e0 * is; o.y = e1 * is; o.z = e2 * is; o.w = e3 * is;
        *(float4*)(out + r * NCLS) = o;
    }
}

extern "C" void kernel_launch(void* const* d_in, const int* in_sizes, int n_in,
                              void* d_out, int out_size, void* d_ws, size_t ws_size,
                              hipStream_t stream) {
    const float* x    = (const float*)d_in[0];
    const float* W_ih = (const float*)d_in[1];
    const float* W_hh = (const float*)d_in[2];
    const float* b_ih = (const float*)d_in[3];
    const float* b_hh = (const float*)d_in[4];
    const float* W_fc = (const float*)d_in[5];
    const float* b_fc = (const float*)d_in[6];
    float* out = (float*)d_out;

    const size_t need = (size_t)BB * TT * HH * 4 * sizeof(f16);   // 262.1 MB
    if (d_ws != nullptr && ws_size >= need) {
        unsigned* xp = (unsigned*)d_ws;
        xproj<<<dim3(TT / TB, BB), 256, 0, stream>>>(x, W_ih, b_ih, b_hh, xp);
        lstm_rec<<<BB, 64, 0, stream>>>((const uint2*)xp, W_hh, W_fc, b_fc, out);
    } else {
        lstm_fb<<<BB, 64, 0, stream>>>(x, W_ih, W_hh, b_ih, b_hh, W_fc, b_fc, out);
    }
}

// Round 9
// 655.432 us; speedup vs baseline: 1.1536x; 1.1536x over previous
//
#include <hip/hip_runtime.h>

// Problem constants
#define BB   512
#define CC   22
#define TT   1000
#define HH   64
#define NCLS 4
#define FCW  (TT * HH)       // 64000: W_fc row length
#define TBX  200             // t-tile per xproj block (5 tiles)
#define TCF  250             // rec: t-chunk for batched FC / h history

typedef _Float16 f16;
typedef __attribute__((ext_vector_type(2))) _Float16 h2;

__device__ __forceinline__ float sigm(float x) {
    float e = __expf(-x);
    return __builtin_amdgcn_rcpf(1.0f + e);
}
__device__ __forceinline__ float tanh_(float x) {
    float e = __expf(-2.0f * fabsf(x));   // (0,1], no overflow
    float r = (1.0f - e) * __builtin_amdgcn_rcpf(1.0f + e);
    return copysignf(r, x);
}
__device__ __forceinline__ h2 u2h(unsigned u) {
    union { unsigned u; h2 h; } c; c.u = u; return c.h;
}
__device__ __forceinline__ unsigned h2u(h2 h) {
    union { unsigned u; h2 h; } c; c.h = h; return c.u;
}
__device__ __forceinline__ unsigned pack2(float a, float b) {
    union { unsigned u; h2 h; } c;
    c.h = h2{(f16)a, (f16)b};
    return c.u;
}

// ---------------------------------------------------------------------------
// R13 kernel 1: x-projection, fdot2 version.
// R12's version was ~165us vs a ~30-50us floor: 88 scalar fma per t per
// thread and narrow stores. v3: x tile transposed into LDS as [t][12] h2
// rows (R4's proven staging pattern), each thread = (tsub, hid) computes all
// 4 gates of its hid via 44 fdot2 per t (broadcast b128 LDS reads), stores
// ONE coalesced uint2 (64 lanes x 8B = 512B/instr).
// Layout matches lstm_rec: uint2 slot (b*TT+t)*64 + hid = {pack2(i,f),
// pack2(g,o)}.
// ---------------------------------------------------------------------------
__global__ __launch_bounds__(256) void xproj(
    const float* __restrict__ x,     // [B, C, T]
    const float* __restrict__ W_ih,  // [4H, C]
    const float* __restrict__ b_ih,  // [4H]
    const float* __restrict__ b_hh,  // [4H]
    uint2* __restrict__ xp)          // [B*T*64] uint2
{
    __shared__ __align__(16) h2 xt[TBX][12];   // 9.6 KB

    const int tid = threadIdx.x;
    const int t0  = blockIdx.x * TBX;
    const int b   = blockIdx.y;
    const int hid = tid & 63;
    const int tsub = tid >> 6;       // 4 t-phases

    // stage: thread t builds row [t][12] (loads coalesced along t per channel)
    if (tid < TBX) {
        const float* gx = x + (size_t)b * (CC * TT) + t0 + tid;
        union { h2 h[12]; uint4 q[3]; } U;
        #pragma unroll
        for (int k = 0; k < 11; ++k)
            U.h[k] = h2{(f16)gx[(2 * k) * TT], (f16)gx[(2 * k + 1) * TT]};
        U.h[11] = h2{(f16)0.0f, (f16)0.0f};
        uint4* dst = (uint4*)&xt[tid][0];
        dst[0] = U.q[0]; dst[1] = U.q[1]; dst[2] = U.q[2];
    }

    // this thread's 4 gate rows (44 regs) + folded biases
    unsigned wih[4][11];
    float bias[4];
    #pragma unroll
    for (int g = 0; g < 4; ++g) {
        const float* wi = W_ih + (g * HH + hid) * CC;
        #pragma unroll
        for (int k = 0; k < 11; ++k)
            wih[g][k] = h2u(h2{(f16)wi[2 * k], (f16)wi[2 * k + 1]});
        bias[g] = b_ih[g * HH + hid] + b_hh[g * HH + hid];
    }
    __syncthreads();

    uint2* op = xp + ((size_t)b * TT + t0) * 64 + hid;
    for (int t = tsub; t < TBX; t += 4) {
        union { uint4 q[3]; h2 h[12]; } X;
        const uint4* xr = (const uint4*)&xt[t][0];   // broadcast b128
        X.q[0] = xr[0]; X.q[1] = xr[1]; X.q[2] = xr[2];
        float a0 = bias[0], a1 = bias[1], a2 = bias[2], a3 = bias[3];
        #pragma unroll
        for (int k = 0; k < 11; ++k) {
            a0 = __builtin_amdgcn_fdot2(X.h[k], u2h(wih[0][k]), a0, false);
            a1 = __builtin_amdgcn_fdot2(X.h[k], u2h(wih[1][k]), a1, false);
            a2 = __builtin_amdgcn_fdot2(X.h[k], u2h(wih[2][k]), a2, false);
            a3 = __builtin_amdgcn_fdot2(X.h[k], u2h(wih[3][k]), a3, false);
        }
        op[(size_t)t * 64] = uint2{pack2(a0, a1), pack2(a2, a3)};
    }
}

// ---------------------------------------------------------------------------
// R13 kernel 2: single-wave recurrence (R11's proven 535us core) with:
//  * FC batched OFF the serial path: per step only a 2B h store into a
//    250-row LDS history that ALSO serves as the h-broadcast buffer (next
//    step reads row tt-1; in-wave in-order DS, zero barriers). The 4 W_fc
//    loads + FMAs per step move to a flat chunk-end loop (compiler-pipelined,
//    coalesced dword loads).
//  * xp prefetched 3 steps ahead via a 6-register rotation (R12's 22-reg
//    pipeline regressed under the 132-VGPR allocator cap). Slack ~2400 cyc
//    covers the ~900-cyc HBM miss measured in R11 (FETCH=132MB).
//  * serial loop retains exactly ONE VMEM op (the xp load).
// ---------------------------------------------------------------------------
__global__ __attribute__((amdgpu_waves_per_eu(1, 1)))
__launch_bounds__(64) void lstm_rec(
    const uint2* __restrict__ xp,    // [B, T, 64] uint2 (4 f16 gates)
    const float* __restrict__ W_hh,  // [4H, H]
    const float* __restrict__ W_fc,  // [NCLS, T*H]
    const float* __restrict__ b_fc,  // [NCLS]
    float* __restrict__ out)         // [B, NCLS]
{
    __shared__ __align__(16) f16 hst[TCF][HH];   // 32 KB: h history + broadcast

    const int lane = threadIdx.x;    // hidden unit
    const int r    = blockIdx.x;     // batch row

    // per-lane recurrent weights (128 VGPR), pinned resident
    unsigned whh[4][32];
    #pragma unroll
    for (int g = 0; g < 4; ++g) {
        const float* wr = W_hh + (g * HH + lane) * HH;
        #pragma unroll
        for (int k = 0; k < 32; ++k)
            whh[g][k] = h2u(h2{(f16)wr[2 * k], (f16)wr[2 * k + 1]});
    }
    #pragma unroll
    for (int g = 0; g < 4; ++g)
        #pragma unroll
        for (int k = 0; k < 32; ++k) asm volatile("" : "+v"(whh[g][k]));

    hst[TCF - 1][lane] = (f16)0.0f;  // h_0 (read by step tt=0 as "prev row")
    float c = 0.0f;
    float fc0 = 0.f, fc1 = 0.f, fc2 = 0.f, fc3 = 0.f;
    const uint2* px = xp + (size_t)r * TT * HH + lane;

    // 3-deep xp pipeline (6 VGPRs)
    uint2 xvA = px[0];
    uint2 xvB = px[HH];
    uint2 xvC = px[2 * HH];

    for (int chunk = 0; chunk < 4; ++chunk) {
        const int T0 = chunk * TCF;

        for (int tt = 0; tt < TCF; ++tt) {
            const int t = T0 + tt;

            // prefetch step t+3 (clamped at tail)
            const int tp = (t + 3 < TT) ? t + 3 : TT - 1;
            const uint2 xvN = px[(size_t)tp * HH];

            // h broadcast: previous step's row (8 x b128, same-address)
            const int pr = (tt == 0) ? TCF - 1 : tt - 1;
            union { uint4 q[8]; h2 h[32]; } H;
            const uint4* hr = (const uint4*)&hst[pr][0];
            #pragma unroll
            for (int i = 0; i < 8; ++i) H.q[i] = hr[i];

            // gates: init from the long-arrived xp value, then 128 fdot2
            const h2 pif = u2h(xvA.x), pgo = u2h(xvA.y);
            float a0 = (float)pif[0], a1 = (float)pif[1];
            float a2 = (float)pgo[0], a3 = (float)pgo[1];
            #pragma unroll
            for (int k = 0; k < 32; ++k) {
                a0 = __builtin_amdgcn_fdot2(H.h[k], u2h(whh[0][k]), a0, false);
                a1 = __builtin_amdgcn_fdot2(H.h[k], u2h(whh[1][k]), a1, false);
                a2 = __builtin_amdgcn_fdot2(H.h[k], u2h(whh[2][k]), a2, false);
                a3 = __builtin_amdgcn_fdot2(H.h[k], u2h(whh[3][k]), a3, false);
            }

            // lane-local LSTM update
            const float iv = sigm(a0), fv = sigm(a1);
            const float gv = tanh_(a2), ov = sigm(a3);
            c = fv * c + iv * gv;
            const float h = ov * tanh_(c);

            // publish h: single 2B store (history row tt = this step's h)
            hst[tt][lane] = (f16)h;

            // rotate xp pipeline
            xvA = xvB; xvB = xvC; xvC = xvN;
        }

        // ---- chunk-end batched FC (off the serial path, coalesced) ----
        const float* w0 = W_fc + 0 * FCW + (size_t)T0 * HH + lane;
        const float* w1 = W_fc + 1 * FCW + (size_t)T0 * HH + lane;
        const float* w2 = W_fc + 2 * FCW + (size_t)T0 * HH + lane;
        const float* w3 = W_fc + 3 * FCW + (size_t)T0 * HH + lane;
        for (int tt = 0; tt < TCF; ++tt) {
            const float hv = (float)hst[tt][lane];
            fc0 += hv * w0[(size_t)tt * HH];
            fc1 += hv * w1[(size_t)tt * HH];
            fc2 += hv * w2[(size_t)tt * HH];
            fc3 += hv * w3[(size_t)tt * HH];
        }
    }

    // FC reduce over hid (wave shuffle) + softmax
    #pragma unroll
    for (int off = 32; off; off >>= 1) {
        fc0 += __shfl_down(fc0, off);
        fc1 += __shfl_down(fc1, off);
        fc2 += __shfl_down(fc2, off);
        fc3 += __shfl_down(fc3, off);
    }
    if (lane == 0) {
        const float l0 = fc0 + b_fc[0], l1 = fc1 + b_fc[1];
        const float l2 = fc2 + b_fc[2], l3 = fc3 + b_fc[3];
        const float m  = fmaxf(fmaxf(l0, l1), fmaxf(l2, l3));
        const float e0 = __expf(l0 - m), e1 = __expf(l1 - m);
        const float e2 = __expf(l2 - m), e3 = __expf(l3 - m);
        const float is = __builtin_amdgcn_rcpf(e0 + e1 + e2 + e3);
        float4 o; o.x = e0 * is; o.y = e1 * is; o.z = e2 * is; o.w = e3 * is;
        *(float4*)(out + r * NCLS) = o;
    }
}

// ---------------------------------------------------------------------------
// Fallback: self-contained single kernel (R4 structure), used only if the
// workspace can't hold xp (262 MB).
// ---------------------------------------------------------------------------
#define TC   250
#define NCHUNK (TT / TC)
#define XROW 12

__global__ __attribute__((amdgpu_waves_per_eu(1, 1)))
__launch_bounds__(64) void lstm_fb(
    const float* __restrict__ x, const float* __restrict__ W_ih,
    const float* __restrict__ W_hh, const float* __restrict__ b_ih,
    const float* __restrict__ b_hh, const float* __restrict__ W_fc,
    const float* __restrict__ b_fc, float* __restrict__ out)
{
    __shared__ __align__(16) h2  xs[TC][XROW];
    __shared__ __align__(16) f16 hbuf[HH];

    const int lane = threadIdx.x;
    const int r    = blockIdx.x;

    unsigned whh[4][32];
    unsigned wih[4][11];
    float bias[4];
    #pragma unroll
    for (int g = 0; g < 4; ++g) {
        const int row = g * HH + lane;
        const float* wr = W_hh + row * HH;
        #pragma unroll
        for (int k = 0; k < 32; ++k)
            whh[g][k] = h2u(h2{(f16)wr[2 * k], (f16)wr[2 * k + 1]});
        const float* wi = W_ih + row * CC;
        #pragma unroll
        for (int k = 0; k < 11; ++k)
            wih[g][k] = h2u(h2{(f16)wi[2 * k], (f16)wi[2 * k + 1]});
        bias[g] = b_ih[row] + b_hh[row];
    }
    #pragma unroll
    for (int g = 0; g < 4; ++g) {
        #pragma unroll
        for (int k = 0; k < 32; ++k) asm volatile("" : "+v"(whh[g][k]));
        #pragma unroll
        for (int k = 0; k < 11; ++k) asm volatile("" : "+v"(wih[g][k]));
        asm volatile("" : "+v"(bias[g]));
    }

    hbuf[lane] = (f16)0.0f;
    float c = 0.0f;
    float fc0 = 0.f, fc1 = 0.f, fc2 = 0.f, fc3 = 0.f;
    const float* p0 = W_fc + 0 * FCW + lane;
    const float* p1 = W_fc + 1 * FCW + lane;
    const float* p2 = W_fc + 2 * FCW + lane;
    const float* p3 = W_fc + 3 * FCW + lane;
    const float* xrow = x + (size_t)r * (CC * TT);

    for (int chunk = 0; chunk < NCHUNK; ++chunk) {
        for (int tb = 0; tb < TC; tb += 64) {
            const int t = tb + lane;
            if (t < TC) {
                const float* gx = xrow + chunk * TC + t;
                union { h2 h[XROW]; uint4 q[3]; } U;
                #pragma unroll
                for (int k = 0; k < 11; ++k)
                    U.h[k] = h2{(f16)gx[(2 * k) * TT], (f16)gx[(2 * k + 1) * TT]};
                U.h[11] = h2{(f16)0.0f, (f16)0.0f};
                uint4* dst = (uint4*)&xs[t][0];
                dst[0] = U.q[0]; dst[1] = U.q[1]; dst[2] = U.q[2];
            }
        }
        for (int tt = 0; tt < TC; ++tt) {
            union { uint4 q[8]; h2 h[32]; } H;
            const uint4* hr = (const uint4*)hbuf;
            #pragma unroll
            for (int i = 0; i < 8; ++i) H.q[i] = hr[i];
            union { uint4 q[3]; h2 h[XROW]; } X;
            const uint4* xr = (const uint4*)&xs[tt][0];
            X.q[0] = xr[0]; X.q[1] = xr[1]; X.q[2] = xr[2];
            float w0 = *p0, w1 = *p1, w2 = *p2, w3 = *p3;
            p0 += HH; p1 += HH; p2 += HH; p3 += HH;
            float a0 = bias[0], a1 = bias[1], a2 = bias[2], a3 = bias[3];
            #pragma unroll
            for (int k = 0; k < 11; ++k) {
                a0 = __builtin_amdgcn_fdot2(X.h[k], u2h(wih[0][k]), a0, false);
                a1 = __builtin_amdgcn_fdot2(X.h[k], u2h(wih[1][k]), a1, false);
                a2 = __builtin_amdgcn_fdot2(X.h[k], u2h(wih[2][k]), a2, false);
                a3 = __builtin_amdgcn_fdot2(X.h[k], u2h(wih[3][k]), a3, false);
            }
            #pragma unroll
            for (int k = 0; k < 32; ++k) {
                a0 = __builtin_amdgcn_fdot2(H.h[k], u2h(whh[0][k]), a0, false);
                a1 = __builtin_amdgcn_fdot2(H.h[k], u2h(whh[1][k]), a1, false);
                a2 = __builtin_amdgcn_fdot2(H.h[k], u2h(whh[2][k]), a2, false);
                a3 = __builtin_amdgcn_fdot2(H.h[k], u2h(whh[3][k]), a3, false);
            }
            const float iv = sigm(a0), fv = sigm(a1);
            const float gv = tanh_(a2), ov = sigm(a3);
            c = fv * c + iv * gv;
            const float h = ov * tanh_(c);
            fc0 += h * w0; fc1 += h * w1; fc2 += h * w2; fc3 += h * w3;
            hbuf[lane] = (f16)h;
        }
    }
    #pragma unroll
    for (int off = 32; off; off >>= 1) {
        fc0 += __shfl_down(fc0, off);
        fc1 += __shfl_down(fc1, off);
        fc2 += __shfl_down(fc2, off);
        fc3 += __shfl_down(fc3, off);
    }
    if (lane == 0) {
        const float l0 = fc0 + b_fc[0], l1 = fc1 + b_fc[1];
        const float l2 = fc2 + b_fc[2], l3 = fc3 + b_fc[3];
        const float m  = fmaxf(fmaxf(l0, l1), fmaxf(l2, l3));
        const float e0 = __expf(l0 - m), e1 = __expf(l1 - m);
        const float e2 = __expf(l2 - m), e3 = __expf(l3 - m);
        const float is = __builtin_amdgcn_rcpf(e0 + e1 + e2 + e3);
        float4 o; o.x = e0 * is; o.y = e1 * is; o.z = e2 * is; o.w = e3 * is;
        *(float4*)(out + r * NCLS) = o;
    }
}

extern "C" void kernel_launch(void* const* d_in, const int* in_sizes, int n_in,
                              void* d_out, int out_size, void* d_ws, size_t ws_size,
                              hipStream_t stream) {
    const float* x    = (const float*)d_in[0];
    const float* W_ih = (const float*)d_in[1];
    const float* W_hh = (const float*)d_in[2];
    const float* b_ih = (const float*)d_in[3];
    const float* b_hh = (const float*)d_in[4];
    const float* W_fc = (const float*)d_in[5];
    const float* b_fc = (const float*)d_in[6];
    float* out = (float*)d_out;

    const size_t need = (size_t)BB * TT * HH * 4 * sizeof(f16);   // 262.1 MB
    if (d_ws != nullptr && ws_size >= need) {
        uint2* xp = (uint2*)d_ws;
        xproj<<<dim3(TT / TBX, BB), 256, 0, stream>>>(x, W_ih, b_ih, b_hh, xp);
        lstm_rec<<<BB, 64, 0, stream>>>(xp, W_hh, W_fc, b_fc, out);
    } else {
        lstm_fb<<<BB, 64, 0, stream>>>(x, W_ih, W_hh, b_ih, b_hh, W_fc, b_fc, out);
    }
}